// Round 4
// baseline (138.257 us; speedup 1.0000x reference)
//
#include <hip/hip_runtime.h>
#include <hip/hip_cooperative_groups.h>
#include <math.h>

namespace cg = cooperative_groups;

#define LOG2E   1.4426950408889634f
#define SQRT2PI 2.5066282746310002f

typedef _Float16 half8 __attribute__((ext_vector_type(8)));
typedef _Float16 half4 __attribute__((ext_vector_type(4)));
typedef float    f32x4 __attribute__((ext_vector_type(4)));

__device__ __forceinline__ float rcp_fast(float x) { return __builtin_amdgcn_rcpf(x); }

__device__ __forceinline__ float tanh_fast(float z) {
  float az = fabsf(z);
  float u  = exp2f(-2.0f * LOG2E * az);   // exp(-2|z|)
  float r  = (1.0f - u) * rcp_fast(1.0f + u);
  return copysignf(r, z);
}

#define DOT4(acc, a, h)                                        \
  acc = fmaf((a).x, (h).x, acc); acc = fmaf((a).y, (h).y, acc); \
  acc = fmaf((a).z, (h).z, acc); acc = fmaf((a).w, (h).w, acc);

// ---------------------------------------------------------------------------
// Single cooperative kernel, 512 blocks x 256 threads, 2 blocks/CU.
// Phase 1: block (b, q) q in [0,32): MLP for 4 points -> f16 table n-slice
//          Eyt/Ext[b][pix][4q..4q+4) for all 256 pixels + vxh/vyh entries.
// grid.sync()
// Phase 2: block (b, yt, xh): 16y x 128x output tile via 16x16x32 f16 MFMA,
//          A = Eyt rows (and aE*vx[k], aE*vy[k] in-register), B = Ext rows.
// ---------------------------------------------------------------------------
__global__ __launch_bounds__(256, 2) void fused_kernel(
    const float* __restrict__ pts,
    const float* __restrict__ W1, const float* __restrict__ b1,
    const float* __restrict__ W2, const float* __restrict__ b2,
    const float* __restrict__ W3, const float* __restrict__ b3,
    const float* __restrict__ Wf, const float* __restrict__ bf,
    const float* __restrict__ bw_p, const float* __restrict__ thr_p,
    _Float16* __restrict__ Eyt, _Float16* __restrict__ Ext,
    _Float16* __restrict__ vxh, _Float16* __restrict__ vyh,
    float* __restrict__ out)
{
  const int bid = blockIdx.x;
  const int tid = threadIdx.x;
  const float bw = fmaxf(bw_p[0], 1e-5f);

  // ---------------- Phase 1: MLP + table slice ----------------
  {
    const int b  = bid >> 5;
    const int q  = bid & 31;
    const int p0 = b * 128 + q * 4;

    __shared__ float sp[4][2];
    __shared__ float sh1[4][64];
    __shared__ float sh2[4][128];
    __shared__ float sh3[4][128];
    __shared__ float sfin[4][2];

    if (tid < 8) sp[tid >> 1][tid & 1] = pts[(p0 + (tid >> 1)) * 2 + (tid & 1)];
    __syncthreads();

    // layer 1: 2 -> 64, relu (one item per thread)
    {
      const int pt = tid >> 6, o = tid & 63;
      float h = fmaf(W1[o * 2 + 1], sp[pt][1], fmaf(W1[o * 2], sp[pt][0], b1[o]));
      sh1[pt][o] = fmaxf(h, 0.0f);
    }
    __syncthreads();

    // layer 2: 64 -> 128, relu (thread owns neuron o for 2 points)
    {
      const int o = tid & 127, g = tid >> 7;
      float4 w[16];
      const float4* wrow = (const float4*)(W2 + o * 64);
#pragma unroll
      for (int i = 0; i < 16; ++i) w[i] = wrow[i];
      float acc[2] = {b2[o], b2[o]};
#pragma unroll
      for (int i = 0; i < 16; ++i) {
        const float4 ww = w[i];
#pragma unroll
        for (int j = 0; j < 2; ++j) {
          const float4 hh = *(const float4*)&sh1[g * 2 + j][i * 4];
          DOT4(acc[j], ww, hh);
        }
      }
#pragma unroll
      for (int j = 0; j < 2; ++j) sh2[g * 2 + j][o] = fmaxf(acc[j], 0.0f);
    }
    __syncthreads();

    // layer 3: 128 -> 128, no relu
    {
      const int o = tid & 127, g = tid >> 7;
      float4 w[32];
      const float4* wrow = (const float4*)(W3 + o * 128);
#pragma unroll
      for (int i = 0; i < 32; ++i) w[i] = wrow[i];
      float acc[2] = {b3[o], b3[o]};
#pragma unroll
      for (int i = 0; i < 32; ++i) {
        const float4 ww = w[i];
#pragma unroll
        for (int j = 0; j < 2; ++j) {
          const float4 hh = *(const float4*)&sh2[g * 2 + j][i * 4];
          DOT4(acc[j], ww, hh);
        }
      }
#pragma unroll
      for (int j = 0; j < 2; ++j) sh3[g * 2 + j][o] = acc[j];
    }
    __syncthreads();

    // final 128 -> 2, fold valid mask and exp(-1e-8/(2 bw^2))
    if (tid < 8) {
      const int pt = tid >> 1, c = tid & 1;
      float acc = bf[c];
      const float4* wv = (const float4*)(Wf + c * 128);
      const float4* h4 = (const float4*)&sh3[pt][0];
#pragma unroll
      for (int i = 0; i < 32; ++i) { float4 a = wv[i]; float4 hh = h4[i]; DOT4(acc, a, hh); }
      const float px = sp[pt][0], py = sp[pt][1];
      const bool valid = (fabsf(px) > 1e-8f) || (fabsf(py) > 1e-8f);
      const float K  = expf(-1e-8f / (2.0f * bw * bw));
      sfin[pt][c] = valid ? acc * K : 0.0f;
    }
    __syncthreads();

    // table slice: thread = pixel coordinate, n in [4q, 4q+4)
    {
      const float c2 = -0.5f / (bw * bw) * LOG2E;
      const float STEP = 2.0f / 255.0f;
      const float g = fmaf((float)tid, STEP, -1.0f);
      half4 ey, ex;
#pragma unroll
      for (int j = 0; j < 4; ++j) {
        const float dy = g - sp[j][1];
        ey[j] = (_Float16)exp2f(c2 * dy * dy);
        const float dx = g - sp[j][0];
        ex[j] = (_Float16)exp2f(c2 * dx * dx);
      }
      const size_t base = ((size_t)b * 256 + tid) * 128 + q * 4;
      *(half4*)&Eyt[base] = ey;
      *(half4*)&Ext[base] = ex;
      if (tid < 8) {
        const int pt = tid >> 1, c = tid & 1;
        if (c == 0) vxh[b * 128 + q * 4 + pt] = (_Float16)sfin[pt][0];
        else        vyh[b * 128 + q * 4 + pt] = (_Float16)sfin[pt][1];
      }
    }
  }

  __threadfence();
  cg::this_grid().sync();

  // ---------------- Phase 2: MFMA field ----------------
  {
    const int b  = bid >> 5;
    const int yt = (bid >> 1) & 15;
    const int xt = bid & 1;
    const int wv   = tid >> 6;
    const int lane = tid & 63;
    const int lr = lane & 15, lg = lane >> 4;
    const int y0 = yt * 16;
    const int x0 = xt * 128 + wv * 32;

    const size_t tb = (size_t)b * 256 * 128;
    const _Float16* pEy = Eyt + tb + (size_t)(y0 + lr) * 128 + lg * 8;
    const size_t brow0 = tb + (size_t)(x0 + lr) * 128 + lg * 8;
    const _Float16* pVxk = vxh + b * 128 + lg * 8;
    const _Float16* pVyk = vyh + b * 128 + lg * 8;

    f32x4 acc[3][2];
#pragma unroll
    for (int c = 0; c < 3; ++c)
#pragma unroll
      for (int n = 0; n < 2; ++n) acc[c][n] = (f32x4){0.f, 0.f, 0.f, 0.f};

#pragma unroll
    for (int kk = 0; kk < 4; ++kk) {
      const int ko = kk * 32;
      const half8 aE  = *(const half8*)(pEy + ko);
      const half8 vxk = *(const half8*)(pVxk + ko);
      const half8 vyk = *(const half8*)(pVyk + ko);
      const half8 aX = aE * vxk;
      const half8 aY = aE * vyk;
      const half8 b0 = *(const half8*)(Ext + brow0 + ko);
      const half8 b1 = *(const half8*)(Ext + brow0 + 16 * 128 + ko);
      acc[0][0] = __builtin_amdgcn_mfma_f32_16x16x32_f16(aE, b0, acc[0][0], 0, 0, 0);
      acc[1][0] = __builtin_amdgcn_mfma_f32_16x16x32_f16(aX, b0, acc[1][0], 0, 0, 0);
      acc[2][0] = __builtin_amdgcn_mfma_f32_16x16x32_f16(aY, b0, acc[2][0], 0, 0, 0);
      acc[0][1] = __builtin_amdgcn_mfma_f32_16x16x32_f16(aE, b1, acc[0][1], 0, 0, 0);
      acc[1][1] = __builtin_amdgcn_mfma_f32_16x16x32_f16(aX, b1, acc[1][1], 0, 0, 0);
      acc[2][1] = __builtin_amdgcn_mfma_f32_16x16x32_f16(aY, b1, acc[2][1], 0, 0, 0);
    }

    const float thr = thr_p[0];
    const float inv_norm = 1.0f / (128.0f * bw * SQRT2PI);
    float* outD = out;
    float* outF = out + (size_t)16 * 65536;

#pragma unroll
    for (int nt = 0; nt < 2; ++nt) {
      const int x = x0 + nt * 16 + lr;
#pragma unroll
      for (int r = 0; r < 4; ++r) {
        const int y = y0 + lg * 4 + r;
        const size_t pidx = (size_t)y * 256 + x;
        const float dn = acc[0][nt][r] * inv_norm;
        outD[(size_t)b * 65536 + pidx] = rcp_fast(1.0f + exp2f((thr - dn) * LOG2E));
        outF[(size_t)b * 131072 + pidx]         = tanh_fast(acc[1][nt][r]);
        outF[(size_t)b * 131072 + 65536 + pidx] = tanh_fast(acc[2][nt][r]);
      }
    }
  }
}

// ---------------------------------------------------------------------------
extern "C" void kernel_launch(void* const* d_in, const int* in_sizes, int n_in,
                              void* d_out, int out_size, void* d_ws, size_t ws_size,
                              hipStream_t stream) {
  const float* pts = (const float*)d_in[0];
  const float* W1  = (const float*)d_in[1];
  const float* b1  = (const float*)d_in[2];
  const float* W2  = (const float*)d_in[3];
  const float* b2  = (const float*)d_in[4];
  const float* W3  = (const float*)d_in[5];
  const float* b3  = (const float*)d_in[6];
  const float* Wf  = (const float*)d_in[7];
  const float* bf  = (const float*)d_in[8];
  const float* bw  = (const float*)d_in[9];
  const float* thr = (const float*)d_in[10];

  _Float16* Eyt = (_Float16*)d_ws;          // 16*256*128 halves = 1 MB
  _Float16* Ext = Eyt + 524288;             // 1 MB
  _Float16* vxh = Ext + 524288;             // 4 KB
  _Float16* vyh = vxh + 2048;               // 4 KB
  float* out = (float*)d_out;

  void* args[] = { (void*)&pts, (void*)&W1, (void*)&b1, (void*)&W2, (void*)&b2,
                   (void*)&W3, (void*)&b3, (void*)&Wf, (void*)&bf, (void*)&bw,
                   (void*)&thr, (void*)&Eyt, (void*)&Ext, (void*)&vxh, (void*)&vyh,
                   (void*)&out };

  hipLaunchCooperativeKernel((const void*)fused_kernel, dim3(512), dim3(256),
                             args, 0, stream);
}

// Round 5
// 24.424 us; speedup vs baseline: 5.6608x; 5.6608x over previous
//
#include <hip/hip_runtime.h>
#include <math.h>

#define LOG2E   1.4426950408889634f
#define SQRT2PI 2.5066282746310002f

typedef _Float16 half8 __attribute__((ext_vector_type(8)));
typedef float    f32x4 __attribute__((ext_vector_type(4)));

__device__ __forceinline__ float rcp_fast(float x) { return __builtin_amdgcn_rcpf(x); }

__device__ __forceinline__ float tanh_fast(float z) {
  float az = fabsf(z);
  float u  = exp2f(-2.0f * LOG2E * az);   // exp(-2|z|)
  float r  = (1.0f - u) * rcp_fast(1.0f + u);
  return copysignf(r, z);
}

#define DOT4(acc, a, h)                                        \
  acc = fmaf((a).x, (h).x, acc); acc = fmaf((a).y, (h).y, acc); \
  acc = fmaf((a).z, (h).z, acc); acc = fmaf((a).w, (h).w, acc);

// ---------------------------------------------------------------------------
// Kernel 1: fused MLP + table slice generation.
// 256 blocks = (image b in 0..15) x (slice q in 0..15); 8 points per block.
// Block computes its 8 points' MLP outputs, writes the n-slice
// [b][pix][8q .. 8q+8) of Eyt/Ext for all 256 pixel coords, and the f16
// point-vector entries vxh/vyh (valid-mask and exp(-1e-8/(2bw^2)) folded in).
// ---------------------------------------------------------------------------
__global__ __launch_bounds__(256) void mlp_table_kernel(
    const float* __restrict__ pts,                      // [2048][2]
    const float* __restrict__ W1, const float* __restrict__ b1,
    const float* __restrict__ W2, const float* __restrict__ b2,
    const float* __restrict__ W3, const float* __restrict__ b3,
    const float* __restrict__ Wf, const float* __restrict__ bf,
    const float* __restrict__ bw_p,
    _Float16* __restrict__ Eyt, _Float16* __restrict__ Ext,
    _Float16* __restrict__ vxh, _Float16* __restrict__ vyh)
{
  __shared__ float sp[8][2];
  __shared__ float sh1[8][64];
  __shared__ float sh2[8][128];
  __shared__ float sh3[8][128];
  __shared__ float sfin[8][2];
  const int tid = threadIdx.x;
  const int b   = blockIdx.x >> 4;
  const int q   = blockIdx.x & 15;
  const int p0  = b * 128 + q * 8;

  if (tid < 16) sp[tid >> 1][tid & 1] = pts[(p0 + (tid >> 1)) * 2 + (tid & 1)];
  __syncthreads();

  // layer 1: 2 -> 64, relu
  for (int t = tid; t < 8 * 64; t += 256) {
    int pt = t >> 6, o = t & 63;
    float h = fmaf(W1[o * 2 + 1], sp[pt][1], fmaf(W1[o * 2], sp[pt][0], b1[o]));
    sh1[pt][o] = fmaxf(h, 0.0f);
  }
  __syncthreads();

  // layer 2: 64 -> 128, relu (thread owns neuron o for 4 points)
  {
    const int o = tid & 127, g = tid >> 7;
    float4 w[16];
    const float4* wrow = (const float4*)(W2 + o * 64);
#pragma unroll
    for (int i = 0; i < 16; ++i) w[i] = wrow[i];
    float acc[4];
#pragma unroll
    for (int j = 0; j < 4; ++j) acc[j] = b2[o];
#pragma unroll
    for (int i = 0; i < 16; ++i) {
      const float4 ww = w[i];
#pragma unroll
      for (int j = 0; j < 4; ++j) {
        const float4 hh = *(const float4*)&sh1[g * 4 + j][i * 4];
        DOT4(acc[j], ww, hh);
      }
    }
#pragma unroll
    for (int j = 0; j < 4; ++j) sh2[g * 4 + j][o] = fmaxf(acc[j], 0.0f);
  }
  __syncthreads();

  // layer 3: 128 -> 128, no relu
  {
    const int o = tid & 127, g = tid >> 7;
    float4 w[32];
    const float4* wrow = (const float4*)(W3 + o * 128);
#pragma unroll
    for (int i = 0; i < 32; ++i) w[i] = wrow[i];
    float acc[4];
#pragma unroll
    for (int j = 0; j < 4; ++j) acc[j] = b3[o];
#pragma unroll
    for (int i = 0; i < 32; ++i) {
      const float4 ww = w[i];
#pragma unroll
      for (int j = 0; j < 4; ++j) {
        const float4 hh = *(const float4*)&sh2[g * 4 + j][i * 4];
        DOT4(acc[j], ww, hh);
      }
    }
#pragma unroll
    for (int j = 0; j < 4; ++j) sh3[g * 4 + j][o] = acc[j];
  }
  __syncthreads();

  // final 128 -> 2, fold valid mask and exp(-1e-8/(2 bw^2)) into vx', vy'
  if (tid < 16) {
    const int pt = tid >> 1, c = tid & 1;
    float acc = bf[c];
    const float4* wv = (const float4*)(Wf + c * 128);
    const float4* h4 = (const float4*)&sh3[pt][0];
#pragma unroll
    for (int i = 0; i < 32; ++i) { float4 a = wv[i]; float4 hh = h4[i]; DOT4(acc, a, hh); }
    const float px = sp[pt][0], py = sp[pt][1];
    const bool valid = (fabsf(px) > 1e-8f) || (fabsf(py) > 1e-8f);
    const float bw = fmaxf(bw_p[0], 1e-5f);
    const float K  = expf(-1e-8f / (2.0f * bw * bw));
    sfin[pt][c] = valid ? acc * K : 0.0f;
  }
  __syncthreads();

  // table slice: thread = pixel coordinate (0..255), n in [8q, 8q+8)
  {
    const float bw = fmaxf(bw_p[0], 1e-5f);
    const float c2 = -0.5f / (bw * bw) * LOG2E;
    const float STEP = 2.0f / 255.0f;
    const float g = fmaf((float)tid, STEP, -1.0f);
    half8 ey, ex;
#pragma unroll
    for (int j = 0; j < 8; ++j) {
      const float dy = g - sp[j][1];
      ey[j] = (_Float16)exp2f(c2 * dy * dy);
      const float dx = g - sp[j][0];
      ex[j] = (_Float16)exp2f(c2 * dx * dx);
    }
    const size_t base = ((size_t)b * 256 + tid) * 128 + q * 8;
    *(half8*)&Eyt[base] = ey;
    *(half8*)&Ext[base] = ex;
    if (tid < 16) {
      const int pt = tid >> 1, c = tid & 1;
      if (c == 0) vxh[p0 + pt] = (_Float16)sfin[pt][0];
      else        vyh[p0 + pt] = (_Float16)sfin[pt][1];
    }
  }
}

// ---------------------------------------------------------------------------
// Kernel 2: MFMA field kernel. 512 blocks (16 img x 16 ytile x 2 xhalf),
// 256 threads = 4 waves; wave covers 32 columns (2 N-tiles of 16), 16 rows.
// No LDS. A = Eyt rows (aX/aY = aE * vx/vy[k] in-register), B = Ext rows.
// ---------------------------------------------------------------------------
__global__ __launch_bounds__(256) void field_mfma_kernel(
    const _Float16* __restrict__ Eyt, const _Float16* __restrict__ Ext,
    const _Float16* __restrict__ vxh, const _Float16* __restrict__ vyh,
    const float* __restrict__ bw_p, const float* __restrict__ thr_p,
    float* __restrict__ out)
{
  const int bid = blockIdx.x;          // [0, 512)
  const int b   = bid >> 5;
  const int yt  = (bid >> 1) & 15;
  const int xt  = bid & 1;
  const int wv   = threadIdx.x >> 6;
  const int lane = threadIdx.x & 63;
  const int lr = lane & 15, lg = lane >> 4;
  const int y0 = yt * 16;
  const int x0 = xt * 128 + wv * 32;

  const size_t tb = (size_t)b * 256 * 128;
  const _Float16* pEy = Eyt + tb + (size_t)(y0 + lr) * 128 + lg * 8;
  const size_t brow0 = tb + (size_t)(x0 + lr) * 128 + lg * 8;
  const _Float16* pVxk = vxh + b * 128 + lg * 8;
  const _Float16* pVyk = vyh + b * 128 + lg * 8;

  f32x4 acc[3][2];
#pragma unroll
  for (int c = 0; c < 3; ++c)
#pragma unroll
    for (int n = 0; n < 2; ++n) acc[c][n] = (f32x4){0.f, 0.f, 0.f, 0.f};

#pragma unroll
  for (int kk = 0; kk < 4; ++kk) {
    const int ko = kk * 32;
    const half8 aE  = *(const half8*)(pEy + ko);
    const half8 vxk = *(const half8*)(pVxk + ko);
    const half8 vyk = *(const half8*)(pVyk + ko);
    const half8 aX = aE * vxk;
    const half8 aY = aE * vyk;
    const half8 b0 = *(const half8*)(Ext + brow0 + ko);
    const half8 b1 = *(const half8*)(Ext + brow0 + 16 * 128 + ko);
    acc[0][0] = __builtin_amdgcn_mfma_f32_16x16x32_f16(aE, b0, acc[0][0], 0, 0, 0);
    acc[1][0] = __builtin_amdgcn_mfma_f32_16x16x32_f16(aX, b0, acc[1][0], 0, 0, 0);
    acc[2][0] = __builtin_amdgcn_mfma_f32_16x16x32_f16(aY, b0, acc[2][0], 0, 0, 0);
    acc[0][1] = __builtin_amdgcn_mfma_f32_16x16x32_f16(aE, b1, acc[0][1], 0, 0, 0);
    acc[1][1] = __builtin_amdgcn_mfma_f32_16x16x32_f16(aX, b1, acc[1][1], 0, 0, 0);
    acc[2][1] = __builtin_amdgcn_mfma_f32_16x16x32_f16(aY, b1, acc[2][1], 0, 0, 0);
  }

  const float bw  = fmaxf(bw_p[0], 1e-5f);
  const float thr = thr_p[0];
  const float inv_norm = 1.0f / (128.0f * bw * SQRT2PI);
  float* outD = out;
  float* outF = out + (size_t)16 * 65536;

#pragma unroll
  for (int nt = 0; nt < 2; ++nt) {
    const int x = x0 + nt * 16 + lr;
#pragma unroll
    for (int r = 0; r < 4; ++r) {
      const int y = y0 + lg * 4 + r;
      const size_t pidx = (size_t)y * 256 + x;
      const float dn = acc[0][nt][r] * inv_norm;
      outD[(size_t)b * 65536 + pidx] = rcp_fast(1.0f + exp2f((thr - dn) * LOG2E));
      outF[(size_t)b * 131072 + pidx]         = tanh_fast(acc[1][nt][r]);
      outF[(size_t)b * 131072 + 65536 + pidx] = tanh_fast(acc[2][nt][r]);
    }
  }
}

// ---------------------------------------------------------------------------
extern "C" void kernel_launch(void* const* d_in, const int* in_sizes, int n_in,
                              void* d_out, int out_size, void* d_ws, size_t ws_size,
                              hipStream_t stream) {
  const float* pts = (const float*)d_in[0];
  const float* W1  = (const float*)d_in[1];
  const float* b1  = (const float*)d_in[2];
  const float* W2  = (const float*)d_in[3];
  const float* b2  = (const float*)d_in[4];
  const float* W3  = (const float*)d_in[5];
  const float* b3  = (const float*)d_in[6];
  const float* Wf  = (const float*)d_in[7];
  const float* bf  = (const float*)d_in[8];
  const float* bw  = (const float*)d_in[9];
  const float* thr = (const float*)d_in[10];

  _Float16* Eyt = (_Float16*)d_ws;          // 16*256*128 halves = 1 MB
  _Float16* Ext = Eyt + 524288;             // 1 MB
  _Float16* vxh = Ext + 524288;             // 4 KB
  _Float16* vyh = vxh + 2048;               // 4 KB

  hipLaunchKernelGGL(mlp_table_kernel, dim3(256), dim3(256), 0, stream,
                     pts, W1, b1, W2, b2, W3, b3, Wf, bf, bw,
                     Eyt, Ext, vxh, vyh);

  hipLaunchKernelGGL(field_mfma_kernel, dim3(512), dim3(256), 0, stream,
                     Eyt, Ext, vxh, vyh, bw, thr, (float*)d_out);
}